// Round 1
// baseline (299.501 us; speedup 1.0000x reference)
//
#include <hip/hip_runtime.h>
#include <hip/hip_bf16.h>

typedef __attribute__((ext_vector_type(8))) short short8;   // 8 x bf16 (4 VGPRs) MFMA frag
typedef __attribute__((ext_vector_type(4))) float f32x4;    // MFMA accumulator
typedef __attribute__((ext_vector_type(4))) unsigned short us4;

#define GK 1024   // K dim of both GEMMs (= word dim)

// ---------- helpers ----------
__device__ __forceinline__ unsigned short f2bf(float f) {       // RNE f32->bf16
  unsigned int u = __float_as_uint(f);
  u += 0x7fffu + ((u >> 16) & 1u);
  return (unsigned short)(u >> 16);
}

__device__ __forceinline__ void gload16(const void* g, void* lds_base /*wave-uniform*/) {
  __builtin_amdgcn_global_load_lds(
      (const __attribute__((address_space(1))) unsigned int*)g,
      (__attribute__((address_space(3))) unsigned int*)lds_base, 16, 0, 0);
}

// ---------- kernel 1: cast f32 -> bf16 (x) ----------
__global__ void cast4_f32_bf16(const float* __restrict__ in, unsigned short* __restrict__ out, int n) {
  int i = (blockIdx.x * 256 + threadIdx.x) * 4;
  if (i >= n) return;
  float4 v = *(const float4*)(in + i);
  us4 o = { f2bf(v.x), f2bf(v.y), f2bf(v.z), f2bf(v.w) };
  *(us4*)(out + i) = o;
}

// ---------- kernel 2: transpose+cast W[K][N] f32 -> Wt[N][K] bf16 ----------
__global__ void transcast(const float* __restrict__ in, unsigned short* __restrict__ out, int K, int N) {
  __shared__ float t[32][33];
  int n0 = blockIdx.x * 32, k0 = blockIdx.y * 32;
  int tx = threadIdx.x, ty = threadIdx.y;
#pragma unroll
  for (int i = 0; i < 4; ++i)
    t[ty * 4 + i][tx] = in[(size_t)(k0 + ty * 4 + i) * N + n0 + tx];
  __syncthreads();
#pragma unroll
  for (int i = 0; i < 4; ++i)
    out[(size_t)(n0 + ty * 4 + i) * K + k0 + tx] = f2bf(t[tx][ty * 4 + i]);
}

// ---------- GEMM (NT): C[M][N] = A[M][1024] * Bt[N][1024]^T + bias ----------
// 128x128 tile, BK=32, 4 waves (2x2), 16x16x32 bf16 MFMA, global_load_lds staging (m97 structure)
template <int OUT_BF16>
__global__ __launch_bounds__(256) void gemm_nt(
    const unsigned short* __restrict__ A,
    const unsigned short* __restrict__ Bt,
    const float* __restrict__ bias,
    void* __restrict__ C, int M, int N)
{
  __shared__ __align__(16) unsigned short Asm[128 * 32];
  __shared__ __align__(16) unsigned short Bsm[128 * 32];
  int bm = blockIdx.x, bn = blockIdx.y;
  int t = threadIdx.x, w = t >> 6, l = t & 63;
  int wm = w >> 1, wn = w & 1;
  int g = l >> 4, ln = l & 15;

  const unsigned short* Ablk = A + (size_t)(bm * 128) * GK;
  const unsigned short* Bblk = Bt + (size_t)(bn * 128) * GK;

  f32x4 acc[4][4] = {};

  int r0 = (w << 4) + (l >> 2);      // staging row within chunk group
  int kc = (l & 3) * 8;              // staging k offset (elems)

  for (int kt = 0; kt < GK / 32; ++kt) {
    __syncthreads();
    int k0 = kt * 32 + kc;
    // A tile: chunks w and w+4 (each chunk = 16 rows x 32 k = 1KB)
    gload16(Ablk + (size_t)r0 * GK + k0,        Asm + w * 512);
    gload16(Ablk + (size_t)(r0 + 64) * GK + k0, Asm + (4 + w) * 512);
    gload16(Bblk + (size_t)r0 * GK + k0,        Bsm + w * 512);
    gload16(Bblk + (size_t)(r0 + 64) * GK + k0, Bsm + (4 + w) * 512);
    __syncthreads();

    short8 af[4], bf[4];
    int ar = wm * 64 + ln;
    int br = wn * 64 + ln;
    int kk = g * 8;
#pragma unroll
    for (int mt = 0; mt < 4; ++mt)
      af[mt] = *(const short8*)(Asm + (ar + mt * 16) * 32 + kk);
#pragma unroll
    for (int nt = 0; nt < 4; ++nt)
      bf[nt] = *(const short8*)(Bsm + (br + nt * 16) * 32 + kk);
#pragma unroll
    for (int mt = 0; mt < 4; ++mt)
#pragma unroll
      for (int nt = 0; nt < 4; ++nt)
        acc[mt][nt] = __builtin_amdgcn_mfma_f32_16x16x32_bf16(af[mt], bf[nt], acc[mt][nt], 0, 0, 0);
  }

  // epilogue: C/D layout col = lane&15, row = (lane>>4)*4 + reg (verified m89/m91)
  int rowb = bm * 128 + wm * 64 + (g << 2);
  int colb = bn * 128 + wn * 64 + ln;
#pragma unroll
  for (int nt = 0; nt < 4; ++nt) {
    int col = colb + nt * 16;
    float bv = bias[col];
#pragma unroll
    for (int mt = 0; mt < 4; ++mt) {
      int row = rowb + mt * 16;
#pragma unroll
      for (int r = 0; r < 4; ++r) {
        float v = acc[mt][nt][r] + bv;
        if (OUT_BF16) ((unsigned short*)C)[(size_t)(row + r) * N + col] = f2bf(v);
        else          ((float*)C)[(size_t)(row + r) * N + col] = v;
      }
    }
  }
}

// ---------- kernel: transpose V slice of qkv -> Vt[(b*16+h)*64 + d][S] ----------
__global__ void transpose_v(const unsigned short* __restrict__ qkvb, unsigned short* __restrict__ Vt) {
  __shared__ __align__(16) unsigned short tile[64][72];   // [s][d], padded
  int blk = blockIdx.x;              // (b*16+h)*16 + s_tile
  int st = blk & 15, bh = blk >> 4, h = bh & 15, b = bh >> 4;
  int t = threadIdx.x;
  int srow = t >> 2, c0 = (t & 3) * 2;

  const unsigned short* src = qkvb + (size_t)(b * 1024 + st * 64 + srow) * 3072 + 2048 + h * 64;
#pragma unroll
  for (int j = 0; j < 2; ++j)
    *(short8*)(&tile[srow][(c0 + j) * 8]) = *(const short8*)(src + (c0 + j) * 8);
  __syncthreads();

  int d = t >> 2;
  unsigned short* dst = Vt + (size_t)(bh * 64 + d) * 1024 + st * 64;
#pragma unroll
  for (int j = 0; j < 2; ++j) {
    int s0 = (c0 + j) * 8;
    short8 v;
#pragma unroll
    for (int i = 0; i < 8; ++i) v[i] = tile[s0 + i][d];
    *(short8*)(dst + s0) = v;
  }
}

// ---------- flash attention: per (b,h,qtile of 64 rows), 4 waves x 16 q-rows ----------
__global__ __launch_bounds__(256) void attn(
    const unsigned short* __restrict__ qkv,  // [8192][3072] bf16
    const unsigned short* __restrict__ Vt,   // [(b*16+h)*64 + d][1024] bf16
    unsigned short* __restrict__ Ob)         // [8192][1024] bf16
{
  __shared__ __align__(16) unsigned short Ksm[64 * 64];    // [key][d], XOR-swizzled chunks
  __shared__ __align__(16) unsigned short Vsm[64 * 64];    // [d][key], XOR-swizzled chunks
  __shared__ __align__(16) unsigned short Psm[4][16 * 64]; // per-wave P [qrow][key]

  int blk = blockIdx.x;                    // (b*16+h)*16 + qt
  int qt = blk & 15, bh = blk >> 4, h = bh & 15, b = bh >> 4;
  int t = threadIdx.x, w = t >> 6, l = t & 63;
  int g = l >> 4, ln = l & 15;

  // Q fragments in registers: A[m=ln][k = 8g+e (+32)]
  const unsigned short* qbase =
      qkv + (size_t)(b * 1024 + qt * 64 + w * 16 + ln) * 3072 + h * 64 + g * 8;
  short8 qf0 = *(const short8*)(qbase);
  short8 qf1 = *(const short8*)(qbase + 32);

  f32x4 acc_o[4] = {};
  float m_r[4], l_r[4];
#pragma unroll
  for (int r = 0; r < 4; ++r) { m_r[r] = -3.0e38f; l_r[r] = 0.f; }

  const unsigned short* Kg = qkv + (size_t)(b * 1024) * 3072 + 1024 + h * 64;
  const unsigned short* Vg = Vt + (size_t)(bh * 64) * 1024;

  int srow = t >> 2;           // staging row 0..63
  int sc0 = (t & 3) * 2;       // staging chunk pair

  for (int kt = 0; kt <= qt; ++kt) {
    __syncthreads();
    {
      const unsigned short* kg = Kg + (size_t)(kt * 64 + srow) * 3072;
      const unsigned short* vg = Vg + (size_t)srow * 1024 + kt * 64;
#pragma unroll
      for (int j = 0; j < 2; ++j) {
        int c = sc0 + j;
        *(short8*)(Ksm + srow * 64 + ((c ^ (srow & 7)) * 8)) = *(const short8*)(kg + c * 8);
        *(short8*)(Vsm + srow * 64 + ((c ^ (srow & 7)) * 8)) = *(const short8*)(vg + c * 8);
      }
    }
    __syncthreads();

    // S = Q K^T  (M=16 q rows, N=64 keys, K=dh 64)
    f32x4 s[4] = {};
#pragma unroll
    for (int nt = 0; nt < 4; ++nt) {
      int krow = nt * 16 + ln;
      short8 b0 = *(const short8*)(Ksm + krow * 64 + ((g ^ (krow & 7)) * 8));
      short8 b1 = *(const short8*)(Ksm + krow * 64 + (((4 + g) ^ (krow & 7)) * 8));
      s[nt] = __builtin_amdgcn_mfma_f32_16x16x32_bf16(qf0, b0, s[nt], 0, 0, 0);
      s[nt] = __builtin_amdgcn_mfma_f32_16x16x32_bf16(qf1, b1, s[nt], 0, 0, 0);
    }

    // scale + causal mask (exactly -1e9 like the reference additive mask)
    bool diag = (kt == qt);
#pragma unroll
    for (int nt = 0; nt < 4; ++nt)
#pragma unroll
      for (int r = 0; r < 4; ++r) {
        float v = s[nt][r] * 0.125f;
        if (diag && (nt * 16 + ln > w * 16 + g * 4 + r)) v = -1.0e9f;
        s[nt][r] = v;
      }

    // online softmax, rows owned per (g, r); reduce across the 16 lanes of the group
#pragma unroll
    for (int r = 0; r < 4; ++r) {
      float mx = fmaxf(fmaxf(s[0][r], s[1][r]), fmaxf(s[2][r], s[3][r]));
#pragma unroll
      for (int off = 8; off >= 1; off >>= 1) mx = fmaxf(mx, __shfl_xor(mx, off, 64));
      float mnew = fmaxf(m_r[r], mx);
      float corr = __expf(m_r[r] - mnew);
      m_r[r] = mnew;
      float rs = 0.f;
#pragma unroll
      for (int nt = 0; nt < 4; ++nt) {
        float p = __expf(s[nt][r] - mnew);
        s[nt][r] = p;
        rs += p;
      }
#pragma unroll
      for (int off = 8; off >= 1; off >>= 1) rs += __shfl_xor(rs, off, 64);
      l_r[r] = l_r[r] * corr + rs;
#pragma unroll
      for (int nt = 0; nt < 4; ++nt) acc_o[nt][r] *= corr;
    }

    // write P (bf16) to per-wave swizzled LDS, then PV MFMA
    unsigned short* P = Psm[w];
#pragma unroll
    for (int nt = 0; nt < 4; ++nt) {
      int col = nt * 16 + ln;
#pragma unroll
      for (int r = 0; r < 4; ++r) {
        int prow = g * 4 + r;
        P[prow * 64 + (((col >> 3) ^ (prow & 7)) * 8) + (col & 7)] = f2bf(s[nt][r]);
      }
    }
    short8 pa[2];
#pragma unroll
    for (int ks = 0; ks < 2; ++ks)
      pa[ks] = *(const short8*)(P + ln * 64 + ((((ks * 4) + g) ^ (ln & 7)) * 8));
#pragma unroll
    for (int nt = 0; nt < 4; ++nt) {
      int vrow = nt * 16 + ln;   // d dimension row of Vsm
#pragma unroll
      for (int ks = 0; ks < 2; ++ks) {
        short8 vb = *(const short8*)(Vsm + vrow * 64 + ((((ks * 4) + g) ^ (vrow & 7)) * 8));
        acc_o[nt] = __builtin_amdgcn_mfma_f32_16x16x32_bf16(pa[ks], vb, acc_o[nt], 0, 0, 0);
      }
    }
  }

  // normalize + store
  float inv[4];
#pragma unroll
  for (int r = 0; r < 4; ++r) inv[r] = 1.0f / l_r[r];
  int orow = b * 1024 + qt * 64 + w * 16;
#pragma unroll
  for (int nt = 0; nt < 4; ++nt) {
    int col = h * 64 + nt * 16 + ln;
#pragma unroll
    for (int r = 0; r < 4; ++r)
      Ob[(size_t)(orow + g * 4 + r) * 1024 + col] = f2bf(acc_o[nt][r] * inv[r]);
  }
}

// ---------- launcher ----------
extern "C" void kernel_launch(void* const* d_in, const int* in_sizes, int n_in,
                              void* d_out, int out_size, void* d_ws, size_t ws_size,
                              hipStream_t stream) {
  (void)in_sizes; (void)n_in; (void)out_size; (void)ws_size;
  const float* x    = (const float*)d_in[0];
  const float* Wqkv = (const float*)d_in[1];
  const float* bqkv = (const float*)d_in[2];
  const float* Wout = (const float*)d_in[3];
  const float* bout = (const float*)d_in[4];

  char* ws = (char*)d_ws;
  unsigned short* xb   = (unsigned short*)(ws);                 // 16 MB  [8192][1024]
  unsigned short* Wt1  = (unsigned short*)(ws + 16777216);      //  6 MB  [3072][1024]
  unsigned short* Wt2  = (unsigned short*)(ws + 23068672);      //  2 MB  [1024][1024]
  unsigned short* qkvb = (unsigned short*)(ws + 25165824);      // 50 MB  [8192][3072]
  unsigned short* Vt   = (unsigned short*)(ws + 75497472);      // 16 MB  [128*64][1024]
  unsigned short* Ob   = (unsigned short*)(ws + 92274688);      // 16 MB  [8192][1024]

  cast4_f32_bf16<<<8192, 256, 0, stream>>>(x, xb, 8192 * 1024);
  transcast<<<dim3(96, 32), dim3(32, 8), 0, stream>>>(Wqkv, Wt1, 1024, 3072);
  transcast<<<dim3(32, 32), dim3(32, 8), 0, stream>>>(Wout, Wt2, 1024, 1024);

  gemm_nt<1><<<dim3(64, 24), 256, 0, stream>>>(xb, Wt1, bqkv, qkvb, 8192, 3072);
  transpose_v<<<2048, 256, 0, stream>>>(qkvb, Vt);
  attn<<<2048, 256, 0, stream>>>(qkvb, Vt, Ob);
  gemm_nt<0><<<dim3(64, 8), 256, 0, stream>>>(Ob, Wt2, bout, (float*)d_out, 8192, 1024);
}